// Round 1
// 494.562 us; speedup vs baseline: 1.1749x; 1.1749x over previous
//
#include <hip/hip_runtime.h>
#include <hip/hip_bf16.h>

// Problem constants
#define NB   8      // batch
#define NH   252    // height
#define NW   192    // width
#define NC   64     // channels
#define HHD  84     // hh = H/3
#define WWD  64     // ww = W/3
#define NE   192    // embed
#define NO   486    // K^4 * HEADS
#define NWIN (NB*HHD*WWD)   // 43008 windows
#define SCALE_F 0.17677669529663687f  // 32^-0.5

typedef __bf16 bf16x8 __attribute__((ext_vector_type(8)));
typedef float floatx4 __attribute__((ext_vector_type(4)));

// Precomputed weights (bf16, written by kt_prep each call):
//   g_WT[e][h*64+c]  = sum_d v_w[c][h*32+d] * out_w[h*32+d][e]   (fused V+output proj)
//   g_awT[n][c]      = attn_w[c][n]                               (logit weights, transposed)
__device__ __attribute__((aligned(16))) __hip_bfloat16 g_WT[NE * 384];
__device__ __attribute__((aligned(16))) __hip_bfloat16 g_awT[NO * 64];

__device__ __forceinline__ bf16x8 bf16x8_zero() {
    bf16x8 z;
    #pragma unroll
    for (int j = 0; j < 8; ++j) z[j] = (__bf16)0.f;
    return z;
}

// ---------------------------------------------------------------------------
// Kernel T: build g_WT (fp32 accumulate of v_w @ out_w per head, then bf16)
// and g_awT (transpose+cvt of attn_w).
// ---------------------------------------------------------------------------
__global__ __launch_bounds__(256) void kt_prep(
    const float* __restrict__ vw, const float* __restrict__ ow,
    const float* __restrict__ aw)
{
    int t = blockIdx.x * 256 + threadIdx.x;
    if (t < NE * 384) {
        int e  = t / 384;
        int hc = t - e * 384;        // h*64 + c
        int h  = hc >> 6;
        int c  = hc & 63;
        float s = 0.f;
        #pragma unroll
        for (int d = 0; d < 32; ++d)
            s = fmaf(vw[c * NE + h * 32 + d], ow[(h * 32 + d) * NE + e], s);
        g_WT[e * 384 + hc] = __float2bfloat16(s);
    } else {
        int tt = t - NE * 384;
        if (tt < NO * 64) {
            int n = tt >> 6;
            int c = tt & 63;
            g_awT[tt] = __float2bfloat16(aw[c * NO + n]);
        }
    }
}

// ---------------------------------------------------------------------------
// Kernel A (fused everything): per block = 8 windows = 72 pixel rows.
//   ph0:  x -> xwT bf16 [c][pixel] (transposed; cols 72..103 zeroed)
//   ph0.5: pooled (mean of 9 pixels) -> pooledB bf16 [win][c]
//   ph1:  logits = pooled @ attn_w via MFMA (A=pooledB, B=g_awT) -> attnS bf16
//   ph2:  softmax over groups of 9 (fp32 math, bf16 store)
//   per head h (6x):
//     A: scatter softmax weights into block-diagonal attnBD [80][104]
//     B: P_h = attnBD @ x  via MFMA (B-frags = xwT)   -> Ph bf16 [80][72]
//     C: accF += Ph @ W_h  via MFMA (B-frags = g_WT)  (persistent registers)
//   epilogue: out = accF + out_b, fp32 scatter-store
// LDS: 13312+1024+7776+16640+11520 = 50272 B -> 3 blocks/CU.
// ---------------------------------------------------------------------------
__global__ __launch_bounds__(256, 3) void ka_fused(
    const float* __restrict__ x,
    const float* __restrict__ attn_b,
    const float* __restrict__ out_b,
    float* __restrict__ out)
{
    __shared__ __attribute__((aligned(16))) __bf16 xwT[64 * 104];    // [c][pixel] 13312 B
    __shared__ __attribute__((aligned(16))) __bf16 pooledB[8 * 64];  // [win][c]    1024 B
    __shared__ __attribute__((aligned(16))) __bf16 attnS[8 * 486];   // [win][o]    7776 B
    __shared__ __attribute__((aligned(16))) __bf16 attnBD[80 * 104]; // blockdiag  16640 B
    __shared__ __attribute__((aligned(16))) __bf16 Ph[80 * 72];      // [pix][c]   11520 B

    const int tid  = threadIdx.x;
    const int lane = tid & 63;
    const int wv   = tid >> 6;
    const int m16  = lane & 15;
    const int quad = lane >> 4;
    const int wbase = blockIdx.x * 8;

    // All 8 windows of a block share (b, i); j = jB + win (5376 % 8 == 0).
    const int bB   = wbase / 5376;
    const int remB = wbase - bB * 5376;
    const int iB   = remB >> 6;
    const int jB   = remB & 63;
    const int xbase = ((bB * NH + iB * 3) * NW + jB * 3) * NC;

    // --- Phase 0: load x (coalesced over c) -> xwT transposed; zero pads ---
    #pragma unroll
    for (int it = 0; it < 18; ++it) {
        int row = it * 4 + wv;               // window-local pixel row 0..71
        int win = row / 9;
        int q   = row - win * 9;
        int pr  = q / 3;
        int pc  = q - pr * 3;
        float xv = x[xbase + (pr * NW + win * 3 + pc) * NC + lane];
        xwT[lane * 104 + row] = (__bf16)xv;
    }
    {   // zero xwT cols 72..103 (K-padding for the block-diag GEMM)
        int rr = tid >> 2, ss = tid & 3;
        *(uint4*)(&xwT[rr * 104 + 72 + ss * 8]) = make_uint4(0u, 0u, 0u, 0u);
    }
    // zero attnBD fully once (off-diagonal stays zero across all heads)
    #pragma unroll
    for (int it = 0; it < 5; ++it) {
        int ch = it * 256 + tid;             // 16B chunks, 80*104*2/16 = 1040
        if (ch < 1040) *(uint4*)(&attnBD[ch * 8]) = make_uint4(0u, 0u, 0u, 0u);
    }
    __syncthreads();

    // --- Phase 0.5: pooled = mean over 9 pixels (reads are contiguous in xwT) ---
    #pragma unroll
    for (int it = 0; it < 2; ++it) {
        int win = it * 4 + wv;
        float s = 0.f;
        #pragma unroll
        for (int q = 0; q < 9; ++q) s += (float)xwT[lane * 104 + win * 9 + q];
        pooledB[win * 64 + lane] = (__bf16)(s * (1.f / 9.f));
    }
    __syncthreads();

    // --- Phase 1: logits via MFMA.  D[win][n] = sum_c pooled[win][c]*attn_w[c][n] ---
    {
        bf16x8 afragP[2];
        #pragma unroll
        for (int ks = 0; ks < 2; ++ks)      // m16>=8 reads past pooledB: garbage rows 8..15, discarded
            afragP[ks] = *(const bf16x8*)(&pooledB[m16 * 64 + ks * 32 + quad * 8]);
        const __bf16* Aw = (const __bf16*)g_awT;
        #pragma unroll
        for (int i = 0; i < 8; ++i) {
            int tile = wv * 8 + i;           // 31 tiles of 16 cover N=486
            int n = tile * 16 + m16;
            bool nvalid = (tile < 31) && (n < NO);
            bf16x8 b0 = nvalid ? *(const bf16x8*)(Aw + n * 64 + quad * 8)      : bf16x8_zero();
            bf16x8 b1 = nvalid ? *(const bf16x8*)(Aw + n * 64 + 32 + quad * 8) : bf16x8_zero();
            floatx4 acc;
            acc[0] = 0.f; acc[1] = 0.f; acc[2] = 0.f; acc[3] = 0.f;
            acc = __builtin_amdgcn_mfma_f32_16x16x32_bf16(afragP[0], b0, acc, 0, 0, 0);
            acc = __builtin_amdgcn_mfma_f32_16x16x32_bf16(afragP[1], b1, acc, 0, 0, 0);
            if (nvalid && quad < 2) {        // rows 0..7 = windows; rows 8..15 garbage
                float bn = attn_b[n];
                #pragma unroll
                for (int r = 0; r < 4; ++r)
                    attnS[(quad * 4 + r) * NO + n] = (__bf16)((acc[r] + bn) * SCALE_F);
            }
        }
    }
    __syncthreads();

    // --- Phase 2: softmax over groups of 9 (54 groups/window) ---
    #pragma unroll
    for (int it = 0; it < 2; ++it) {
        int t = it * 256 + tid;
        if (t < 432) {
            int win = t / 54;
            int g = t - win * 54;
            __bf16* a = &attnS[win * NO + g * 9];
            float v[9];
            v[0] = (float)a[0];
            float m = v[0];
            #pragma unroll
            for (int q = 1; q < 9; ++q) { v[q] = (float)a[q]; m = fmaxf(m, v[q]); }
            float s = 0.f;
            #pragma unroll
            for (int q = 0; q < 9; ++q) { v[q] = __expf(v[q] - m); s += v[q]; }
            float inv = 1.f / s;
            #pragma unroll
            for (int q = 0; q < 9; ++q) a[q] = (__bf16)(v[q] * inv);
        }
    }
    __syncthreads();

    // --- Head loop: accF += (attn_h @ x) @ W_h ---
    bf16x8 bfragX[3];                        // B-frags of x (shared by all heads)
    #pragma unroll
    for (int ks = 0; ks < 3; ++ks)
        bfragX[ks] = *(const bf16x8*)(&xwT[(wv * 16 + m16) * 104 + ks * 32 + quad * 8]);

    float bias[3];
    #pragma unroll
    for (int nt = 0; nt < 3; ++nt) bias[nt] = out_b[wv * 48 + nt * 16 + m16];

    floatx4 accF[5][3];
    #pragma unroll
    for (int mt = 0; mt < 5; ++mt)
        #pragma unroll
        for (int nt = 0; nt < 3; ++nt) {
            accF[mt][nt][0] = 0.f; accF[mt][nt][1] = 0.f;
            accF[mt][nt][2] = 0.f; accF[mt][nt][3] = 0.f;
        }

    const __bf16* Wt = (const __bf16*)g_WT;

    for (int h = 0; h < 6; ++h) {
        // A: scatter this head's softmax weights into the block-diagonal matrix
        #pragma unroll
        for (int it = 0; it < 3; ++it) {
            int t = it * 256 + tid;
            if (t < 648) {                   // 8 windows * 81
                int win = t / 81;
                int r81 = t - win * 81;
                int p = r81 / 9;
                int q = r81 - p * 9;
                attnBD[(win * 9 + p) * 104 + win * 9 + q] = attnS[win * NO + h * 81 + r81];
            }
        }
        __syncthreads();

        // B: P_h = attnBD @ x   (M=80, N=64 split 16/wave, K=96 zero-padded)
        {
            floatx4 accP[5];
            #pragma unroll
            for (int mt = 0; mt < 5; ++mt) {
                accP[mt][0] = 0.f; accP[mt][1] = 0.f; accP[mt][2] = 0.f; accP[mt][3] = 0.f;
            }
            #pragma unroll
            for (int ks = 0; ks < 3; ++ks)
                #pragma unroll
                for (int mt = 0; mt < 5; ++mt) {
                    bf16x8 af = *(const bf16x8*)(&attnBD[(mt * 16 + m16) * 104 + ks * 32 + quad * 8]);
                    accP[mt] = __builtin_amdgcn_mfma_f32_16x16x32_bf16(af, bfragX[ks], accP[mt], 0, 0, 0);
                }
            #pragma unroll
            for (int mt = 0; mt < 5; ++mt)
                #pragma unroll
                for (int r = 0; r < 4; ++r)
                    Ph[(mt * 16 + quad * 4 + r) * 72 + wv * 16 + m16] = (__bf16)accP[mt][r];
        }
        __syncthreads();

        // C: accF += Ph @ W_h   (M=80, N=192 split 48/wave, K=64)
        #pragma unroll
        for (int ks = 0; ks < 2; ++ks) {
            bf16x8 bw[3];
            #pragma unroll
            for (int nt = 0; nt < 3; ++nt)
                bw[nt] = *(const bf16x8*)(Wt + (wv * 48 + nt * 16 + m16) * 384 + h * 64 + ks * 32 + quad * 8);
            #pragma unroll
            for (int mt = 0; mt < 5; ++mt) {
                bf16x8 af = *(const bf16x8*)(&Ph[(mt * 16 + m16) * 72 + ks * 32 + quad * 8]);
                #pragma unroll
                for (int nt = 0; nt < 3; ++nt)
                    accF[mt][nt] = __builtin_amdgcn_mfma_f32_16x16x32_bf16(af, bw[nt], accF[mt][nt], 0, 0, 0);
            }
        }
        // no sync needed: next head's phase A touches only attnBD (not read here);
        // sync at top of B guards attnBD, and that same sync guards Ph reuse.
    }

    // --- Epilogue: scatter fp32 stores (rows 72..79 are padding, skipped) ---
    const int obase = ((bB * NH + iB * 3) * NW + jB * 3) * NE;
    #pragma unroll
    for (int mt = 0; mt < 5; ++mt)
        #pragma unroll
        for (int r = 0; r < 4; ++r) {
            int row = mt * 16 + quad * 4 + r;
            if (row < 72) {
                int win = row / 9;
                int p = row - win * 9;
                int pr = p / 3;
                int pc = p - pr * 3;
                int base = obase + (pr * NW + win * 3 + pc) * NE;
                #pragma unroll
                for (int nt = 0; nt < 3; ++nt)
                    out[base + wv * 48 + nt * 16 + m16] = accF[mt][nt][r] + bias[nt];
            }
        }
}

extern "C" void kernel_launch(void* const* d_in, const int* in_sizes, int n_in,
                              void* d_out, int out_size, void* d_ws, size_t ws_size,
                              hipStream_t stream)
{
    const float* x      = (const float*)d_in[0];
    const float* v_w    = (const float*)d_in[1];
    const float* attn_w = (const float*)d_in[2];
    const float* attn_b = (const float*)d_in[3];
    const float* out_w  = (const float*)d_in[4];
    const float* out_b  = (const float*)d_in[5];
    float* out = (float*)d_out;
    (void)d_ws; (void)ws_size; (void)in_sizes; (void)n_in; (void)out_size;

    // 410 blocks cover NE*384 + NO*64 = 104832 prep elements
    hipLaunchKernelGGL(kt_prep, dim3(410), dim3(256), 0, stream, v_w, out_w, attn_w);
    hipLaunchKernelGGL(ka_fused, dim3(NWIN / 8), dim3(256), 0, stream,
                       x, attn_b, out_b, out);
}